// Round 1
// baseline (2208.098 us; speedup 1.0000x reference)
//
#include <hip/hip_runtime.h>
#include <math.h>

#define D 2048
#define E 64

// ---------------- kernel 1: K-quarter partial GEMM ----------------
#define NQ 4              // K quarters (across blocks)
#define KQ (D / NQ)       // 512
#define NKC2 4            // kc chunks per block (wave dim)
#define KCH2 (KQ / NKC2)  // 128 rows per wave
#define EQ 16             // experts per wave (4 expert-quarters)
#define T4 4              // tokens per lane
#define TOKB 256          // tokens per block (64 lanes x T4)
#define TP 20             // padded tile row stride (floats) - bank spread

typedef float4 f4;

__device__ __forceinline__ float fget(const float4 v, int j) {
    return j == 0 ? v.x : j == 1 ? v.y : j == 2 ? v.z : v.w;
}

// 16 floats (one W row slice) via per-lane global_load_dwordx4 x4 (vmcnt, in-order)
__device__ __forceinline__ void wldv(float4 (&dst)[4], const float* p) {
#pragma unroll
    for (int c = 0; c < 4; ++c) dst[c] = *(const float4*)(p + 4 * c);
}

// 64 FMAs: 4 tokens x 16 experts, one k-row. W row reused 4x (T-amortized splat).
__device__ __forceinline__ void fmagrp4(float (&acc)[T4][EQ], const float4 (&xc)[T4],
                                        int j, const float4 (&w)[4]) {
#pragma unroll
    for (int g = 0; g < T4; ++g) {
        const float xj = fget(xc[g], j);
#pragma unroll
        for (int c = 0; c < 4; ++c) {
            acc[g][4*c+0] = fmaf(xj, w[c].x, acc[g][4*c+0]);
            acc[g][4*c+1] = fmaf(xj, w[c].y, acc[g][4*c+1]);
            acc[g][4*c+2] = fmaf(xj, w[c].z, acc[g][4*c+2]);
            acc[g][4*c+3] = fmaf(xj, w[c].w, acc[g][4*c+3]);
        }
    }
}

__device__ __forceinline__ void tile_write16(float* t, const float (&a)[EQ], int lane) {
    float4* p = (float4*)(t + lane * TP);   // 80 B stride: 16B aligned, bank-spread
#pragma unroll
    for (int c = 0; c < 4; ++c) {
        float4 v = {a[4*c], a[4*c+1], a[4*c+2], a[4*c+3]};
        p[c] = v;
    }
}

__device__ __forceinline__ void tile_add16(const float* t, float (&a)[EQ], int lane) {
    const float4* p = (const float4*)(t + lane * TP);
#pragma unroll
    for (int c = 0; c < 4; ++c) {
        float4 v = p[c];
        a[4*c] += v.x; a[4*c+1] += v.y; a[4*c+2] += v.z; a[4*c+3] += v.w;
    }
}

__global__ __launch_bounds__(1024, 2)
void gating_mm(const float* __restrict__ x, const float* __restrict__ W,
               float* __restrict__ partial, int ntok)
{
    __shared__ __align__(16) float tiles[8 * 64 * TP];   // 40 KB

    const int tid  = threadIdx.x;
    const int lane = tid & 63;
    const int w    = __builtin_amdgcn_readfirstlane(tid >> 6);
    const int kc   = w >> 2;               // 0..3 : K sub-chunk
    const int eq   = w & 3;                // 0..3 : expert quarter
    const int q    = blockIdx.x & 3;       // K quarter
    const int tok0 = (blockIdx.x >> 2) * TOKB;
    const int krow0 = q * KQ + kc * KCH2;

    // Opaque per-lane offset: forces VECTOR (vmcnt, in-order) W loads, never s_load.
    int eqoff = eq * EQ;
    asm volatile("" : "+v"(eqoff));
    const float* wp = W + (size_t)krow0 * E + eqoff;

    const float* xr[T4];
#pragma unroll
    for (int g = 0; g < T4; ++g)
        xr[g] = x + (size_t)(tok0 + g * 64 + lane) * D + krow0;

    float acc[T4][EQ];
#pragma unroll
    for (int g = 0; g < T4; ++g)
#pragma unroll
        for (int e = 0; e < EQ; ++e) acc[g][e] = 0.f;

    // prime: W rows 0,1 double-buffered; x 2 float4 ahead per token stream
    float4 wb[2][4];
    wldv(wb[0], wp);
    wldv(wb[1], wp + E);
    float4 xv[T4], xn[T4];
#pragma unroll
    for (int g = 0; g < T4; ++g) {
        xv[g] = *(const f4*)(xr[g]);
        xn[g] = *(const f4*)(xr[g] + 4);
    }

#pragma unroll 1
    for (int k4 = 0; k4 < KCH2 / 4; ++k4) {
        float4 xc[T4];
#pragma unroll
        for (int g = 0; g < T4; ++g) { xc[g] = xv[g]; xv[g] = xn[g]; }
        int nx = (k4 + 2 < KCH2 / 4) ? k4 + 2 : KCH2 / 4 - 1;
#pragma unroll
        for (int g = 0; g < T4; ++g) xn[g] = *(const f4*)(xr[g] + nx * 4);
#pragma unroll
        for (int j = 0; j < 4; ++j) {
            fmagrp4(acc, xc, j, wb[j & 1]);       // row 4*k4+j (256 cyc of FMA cover)
            int r = 4 * k4 + j + 2;               // prefetch 2 rows ahead
            if (r > KCH2 - 1) r = KCH2 - 1;
            wldv(wb[j & 1], wp + (size_t)r * E);
        }
    }

    // ---- kc tree (4 -> 1) per token-group, then coalesced slab store ----
    // slab layout: partial[(q*4 + eq)][tok][16]  -> lane-contiguous 64 B stores,
    // and kernel2 reads 4 KB contiguous per wave.
#pragma unroll
    for (int g = 0; g < T4; ++g) {
        __syncthreads();
        if (w >= 8) tile_write16(tiles + (w - 8) * 64 * TP, acc[g], lane);
        __syncthreads();
        if (w < 8)  tile_add16(tiles + w * 64 * TP, acc[g], lane);      // kc0+=kc2, kc1+=kc3
        __syncthreads();
        if (w >= 4 && w < 8) tile_write16(tiles + (w - 4) * 64 * TP, acc[g], lane);
        __syncthreads();
        if (w < 4)  tile_add16(tiles + w * 64 * TP, acc[g], lane);      // kc0+=kc1
        if (w < 4) {
            float* pq = partial + ((size_t)(q * 4 + w) * ntok + tok0 + g * 64 + lane) * EQ;
#pragma unroll
            for (int c = 0; c < 4; ++c) {
                float4 v = {acc[g][4*c], acc[g][4*c+1], acc[g][4*c+2], acc[g][4*c+3]};
                *(float4*)(pq + 4 * c) = v;
            }
        }
    }
}

// ---------------- kernel 2: quarter-reduce + bias + top2 + scatter ----------------
__global__ __launch_bounds__(256, 4)
void gating_topk(const float* __restrict__ partial, const float* __restrict__ Bv,
                 float* __restrict__ out, int ntok)
{
    __shared__ float logits[64][65];
    __shared__ float sw1[64], sw2[64];
    __shared__ int   si1[64], si2[64];

    const int tid  = threadIdx.x;
    const int tok0 = blockIdx.x * 64;
    const int tok  = tid & 63;
    const int qe   = tid >> 6;             // 0..3 expert quarter
    {
        float4 s[4];
        const float* p0 = partial + ((size_t)qe * ntok + tok0 + tok) * EQ;
#pragma unroll
        for (int c = 0; c < 4; ++c) s[c] = *(const float4*)(p0 + 4 * c);
#pragma unroll
        for (int q = 1; q < 4; ++q) {
            const float* p = partial + ((size_t)(q * 4 + qe) * ntok + tok0 + tok) * EQ;
#pragma unroll
            for (int c = 0; c < 4; ++c) {
                float4 v = *(const float4*)(p + 4 * c);
                s[c].x += v.x; s[c].y += v.y; s[c].z += v.z; s[c].w += v.w;
            }
        }
#pragma unroll
        for (int c = 0; c < 4; ++c) {
            float4 bv = *(const float4*)(Bv + qe * EQ + 4 * c);
            logits[tok][qe * EQ + 4*c + 0] = s[c].x + bv.x;
            logits[tok][qe * EQ + 4*c + 1] = s[c].y + bv.y;
            logits[tok][qe * EQ + 4*c + 2] = s[c].z + bv.z;
            logits[tok][qe * EQ + 4*c + 3] = s[c].w + bv.w;
        }
    }
    __syncthreads();

    if (tid < 64) {
        // lane = token: top-2 scan. Strict '>' matches top_k tie-breaking.
        float m1 = -3.4e38f, m2 = -3.4e38f;
        int i1 = 0, i2 = 0;
#pragma unroll
        for (int e = 0; e < E; ++e) {
            float v = logits[tid][e];
            if (v > m1)      { m2 = m1; i2 = i1; m1 = v; i1 = e; }
            else if (v > m2) { m2 = v; i2 = e; }
        }
        float p = 1.0f / (1.0f + expf(m2 - m1));   // stable: m2 <= m1
        sw1[tid] = p; sw2[tid] = 1.0f - p;
        si1[tid] = i1; si2[tid] = i2;
    }
    __syncthreads();

    float4* o4 = (float4*)(out + (size_t)tok0 * E);
#pragma unroll
    for (int p5 = 0; p5 < 4; ++p5) {
        int idx = tid + p5 * 256;        // 0..1023 float4s of the 64x64 tile
        int tl  = idx >> 4;
        int e0  = (idx & 15) * 4;
        int a1 = si1[tl], a2 = si2[tl];
        float v1 = sw1[tl], v2 = sw2[tl];
        float4 v;
        v.x = (e0 + 0 == a1) ? v1 : (e0 + 0 == a2) ? v2 : 0.0f;
        v.y = (e0 + 1 == a1) ? v1 : (e0 + 1 == a2) ? v2 : 0.0f;
        v.z = (e0 + 2 == a1) ? v1 : (e0 + 2 == a2) ? v2 : 0.0f;
        v.w = (e0 + 3 == a1) ? v1 : (e0 + 3 == a2) ? v2 : 0.0f;
        o4[idx] = v;
    }
}

// ---------------- fallback: previous verified single-kernel path ----------------
#define EH 32
#define TOK 64
#define THREADS 1024
#define NKC 8
#define KCH (D / NKC)

typedef float f16v __attribute__((ext_vector_type(16)));

__device__ __forceinline__ void wload(f16v (&dst)[2], const float* p) {
    dst[0] = *(const f16v*)(p);
    dst[1] = *(const f16v*)(p + 16);
}

__device__ __forceinline__ void fmagrp(float (&acc)[EH], float xj,
                                       const f16v (&wb)[2]) {
#pragma unroll
    for (int h = 0; h < 2; ++h)
#pragma unroll
        for (int i = 0; i < 16; ++i)
            acc[h * 16 + i] = fmaf(xj, wb[h][i], acc[h * 16 + i]);
}

__device__ __forceinline__ void tile_write(float* base, const float (&acc)[EH],
                                           int lane) {
#pragma unroll
    for (int c = 0; c < 8; ++c) {
        int s = (c + lane) & 7;
        float4 v = {acc[4 * c], acc[4 * c + 1], acc[4 * c + 2], acc[4 * c + 3]};
        *(float4*)(base + lane * EH + s * 4) = v;
    }
}

__device__ __forceinline__ void tile_add(const float* base, float (&acc)[EH],
                                         int lane) {
#pragma unroll
    for (int c = 0; c < 8; ++c) {
        int s = (c + lane) & 7;
        float4 v = *(const float4*)(base + lane * EH + s * 4);
        acc[4 * c] += v.x; acc[4 * c + 1] += v.y;
        acc[4 * c + 2] += v.z; acc[4 * c + 3] += v.w;
    }
}

__global__ __launch_bounds__(THREADS, 4)
void gating_kernel(const float* __restrict__ x,
                   const float* __restrict__ W,
                   const float* __restrict__ Bv,
                   float* __restrict__ out)
{
    __shared__ __align__(16) char smem[65536];

    const int tid  = threadIdx.x;
    const int lane = tid & 63;
    const int w    = __builtin_amdgcn_readfirstlane(tid >> 6);
    const int eh   = w & 1;
    const int kc   = w >> 1;
    const int tok0 = blockIdx.x * TOK;

    const float* xrow = x + (size_t)(tok0 + lane) * D + kc * KCH;
    const float* wk   = W + (size_t)kc * KCH * E + eh * EH;

    float acc[EH];
#pragma unroll
    for (int e = 0; e < EH; ++e) acc[e] = 0.f;

    f16v wb[2][2];
    wload(wb[0], wk);
    wload(wb[1], wk + E);
    float4 xv = *(const float4*)(xrow);
    float4 xn = *(const float4*)(xrow + 4);

#pragma unroll 1
    for (int k4 = 0; k4 < KCH / 4; ++k4) {
        float4 xc = xv; xv = xn;
        int nx = (k4 + 2 < KCH / 4) ? k4 + 2 : KCH / 4 - 1;
        xn = *(const float4*)(xrow + nx * 4);
#pragma unroll
        for (int j = 0; j < 4; ++j) {
            const float xj = j == 0 ? xc.x : j == 1 ? xc.y
                           : j == 2 ? xc.z : xc.w;
            fmagrp(acc, xj, wb[j & 1]);
            int r = 4 * k4 + j + 2;
            if (r > KCH - 1) r = KCH - 1;
            wload(wb[j & 1], wk + (size_t)r * E);
        }
    }

    float* tiles = (float*)smem;
    __syncthreads();
    if (w >= 8) tile_write(tiles + (w - 8) * 2048, acc, lane);
    __syncthreads();
    if (w < 8)  tile_add(tiles + w * 2048, acc, lane);
    __syncthreads();
    if (w >= 4 && w < 8) tile_write(tiles + (w - 4) * 2048, acc, lane);
    __syncthreads();
    if (w < 4)  tile_add(tiles + w * 2048, acc, lane);
    __syncthreads();
    if (w == 2 || w == 3) tile_write(tiles + (w - 2) * 2048, acc, lane);
    __syncthreads();
    if (w < 2)  tile_add(tiles + w * 2048, acc, lane);
    __syncthreads();

    float* logits = (float*)smem;
    float* sw1 = (float*)(smem + 16640);
    float* sw2 = (float*)(smem + 16896);
    int*   si1 = (int*)  (smem + 17152);
    int*   si2 = (int*)  (smem + 17408);

    if (w < 2) {
#pragma unroll
        for (int e = 0; e < EH; ++e)
            logits[lane * 65 + eh * EH + e] = acc[e];
    }
    __syncthreads();

    if (w == 0) {
        float m1 = -3.4e38f, m2 = -3.4e38f;
        int i1 = 0, i2 = 0;
#pragma unroll
        for (int e = 0; e < E; ++e) {
            float v = logits[lane * 65 + e] + Bv[e];
            if (v > m1)      { m2 = m1; i2 = i1; m1 = v; i1 = e; }
            else if (v > m2) { m2 = v; i2 = e; }
        }
        float p = 1.0f / (1.0f + expf(m2 - m1));
        sw1[lane] = p; sw2[lane] = 1.0f - p;
        si1[lane] = i1; si2[lane] = i2;
    }
    __syncthreads();

    float4* o4 = (float4*)(out + (size_t)tok0 * E);
    {
        int idx = tid;
        int tl  = idx >> 4;
        int e0  = (idx & 15) * 4;
        int a1 = si1[tl], a2 = si2[tl];
        float v1 = sw1[tl], v2 = sw2[tl];
        float4 v;
        v.x = (e0 + 0 == a1) ? v1 : (e0 + 0 == a2) ? v2 : 0.0f;
        v.y = (e0 + 1 == a1) ? v1 : (e0 + 1 == a2) ? v2 : 0.0f;
        v.z = (e0 + 2 == a1) ? v1 : (e0 + 2 == a2) ? v2 : 0.0f;
        v.w = (e0 + 3 == a1) ? v1 : (e0 + 3 == a2) ? v2 : 0.0f;
        o4[idx] = v;
    }
}

extern "C" void kernel_launch(void* const* d_in, const int* in_sizes, int n_in,
                              void* d_out, int out_size, void* d_ws, size_t ws_size,
                              hipStream_t stream) {
    const float* x = (const float*)d_in[0];
    const float* W = (const float*)d_in[1];
    const float* b = (const float*)d_in[2];
    float* out = (float*)d_out;

    const int tokens = in_sizes[0] / D;                       // 16384
    const size_t need = (size_t)16 * tokens * EQ * sizeof(float);  // 16 MB partials

    if (d_ws != nullptr && ws_size >= need && (tokens % TOKB) == 0) {
        const int blocks1 = (tokens / TOKB) * NQ;             // 256
        gating_mm<<<blocks1, 1024, 0, stream>>>(x, W, (float*)d_ws, tokens);
        gating_topk<<<tokens / 64, 256, 0, stream>>>((const float*)d_ws, b, out, tokens);
    } else {
        gating_kernel<<<tokens / TOK, THREADS, 0, stream>>>(x, W, b, out);
    }
}

// Round 2
// 1433.968 us; speedup vs baseline: 1.5399x; 1.5399x over previous
//
#include <hip/hip_runtime.h>
#include <math.h>

#define D 2048
#define E 64
#define EH 32                 // experts per wave (half)
#define TOK 64                // tokens per block (lane = token)
#define THREADS 1024          // 16 waves = 8 K-chunks x 2 expert halves
#define NKC 8
#define KCH (D / NKC)         // 256

// W row slice (32 floats) via per-lane global_load_dwordx4 x8.
// Address carries an opaque VGPR zero so the compiler CANNOT scalarize to
// s_load: vmcnt loads retire in-order -> partial waits, unlike lgkmcnt SMEM
// which forces a full drain before first use (the old 25%-duty stall).
__device__ __forceinline__ void wloadv(float4 (&dst)[8], const float* p) {
#pragma unroll
    for (int c = 0; c < 8; ++c) dst[c] = *(const float4*)(p + 4 * c);
}

// 32 FMAs: acc[e] += xj * wb[e]  (all-VGPR v_fmac)
__device__ __forceinline__ void fmagrp(float (&acc)[EH], float xj,
                                       const float4 (&wb)[8]) {
#pragma unroll
    for (int c = 0; c < 8; ++c) {
        acc[4*c+0] = fmaf(xj, wb[c].x, acc[4*c+0]);
        acc[4*c+1] = fmaf(xj, wb[c].y, acc[4*c+1]);
        acc[4*c+2] = fmaf(xj, wb[c].z, acc[4*c+2]);
        acc[4*c+3] = fmaf(xj, wb[c].w, acc[4*c+3]);
    }
}

// Reduction-tile IO. Tile = [64 tokens][32 floats]; lane owns its row.
// Column-slot swizzle (c+lane)&7 spreads b128 ops over all 32 banks.
__device__ __forceinline__ void tile_write(float* base, const float (&acc)[EH],
                                           int lane) {
#pragma unroll
    for (int c = 0; c < 8; ++c) {
        int s = (c + lane) & 7;
        float4 v = {acc[4 * c], acc[4 * c + 1], acc[4 * c + 2], acc[4 * c + 3]};
        *(float4*)(base + lane * EH + s * 4) = v;
    }
}

__device__ __forceinline__ void tile_add(const float* base, float (&acc)[EH],
                                         int lane) {
#pragma unroll
    for (int c = 0; c < 8; ++c) {
        int s = (c + lane) & 7;
        float4 v = *(const float4*)(base + lane * EH + s * 4);
        acc[4 * c] += v.x; acc[4 * c + 1] += v.y;
        acc[4 * c + 2] += v.z; acc[4 * c + 3] += v.w;
    }
}

__global__ __launch_bounds__(THREADS, 4)
void gating_kernel(const float* __restrict__ x,
                   const float* __restrict__ W,
                   const float* __restrict__ Bv,
                   float* __restrict__ out)
{
    // LDS (64 KB): tree tiles 0..7 at w*8KB. After the final tree barrier,
    // tiles 0..1 area is reused for logits [64][65] and the top-2 arrays.
    __shared__ __align__(16) char smem[65536];

    const int tid  = threadIdx.x;
    const int lane = tid & 63;
    const int w    = __builtin_amdgcn_readfirstlane(tid >> 6);
    const int eh   = w & 1;          // expert half (32 experts)
    const int kc   = w >> 1;         // K-chunk 0..7
    const int tok0 = blockIdx.x * TOK;

    const float* xrow = x + (size_t)(tok0 + lane) * D + kc * KCH;  // per-lane

    // Opaque zero in a VGPR -> W address is "divergent" -> global_load, not s_load.
    int voff = 0;
    asm volatile("" : "+v"(voff));
    const float* wk = W + (size_t)kc * KCH * E + eh * EH + voff;

    float acc[EH];
#pragma unroll
    for (int e = 0; e < EH; ++e) acc[e] = 0.f;

    // ---- K-loop: W 2-row double buffer in VGPRs, x per-lane float4 ----
    float4 wb[2][8];
    wloadv(wb[0], wk);                // row 0
    wloadv(wb[1], wk + E);            // row 1
    float4 xv = *(const float4*)(xrow);
    float4 xn = *(const float4*)(xrow + 4);

#pragma unroll 1
    for (int k4 = 0; k4 < KCH / 4; ++k4) {
        float4 xc = xv; xv = xn;
        int nx = (k4 + 2 < KCH / 4) ? k4 + 2 : KCH / 4 - 1;
        xn = *(const float4*)(xrow + nx * 4);
#pragma unroll
        for (int j = 0; j < 4; ++j) {
            const float xj = j == 0 ? xc.x : j == 1 ? xc.y
                           : j == 2 ? xc.z : xc.w;
            fmagrp(acc, xj, wb[j & 1]);        // uses row 4*k4+j
            int r = 4 * k4 + j + 2;            // prefetch 2 rows ahead
            if (r > KCH - 1) r = KCH - 1;
            wloadv(wb[j & 1], wk + (size_t)r * E);
        }
    }

    // ---- cross-wave K-reduction: 3-level tree, pairing (kc, kc+step) ----
    float* tiles = (float*)smem;               // tile i at i*2048 floats
    __syncthreads();
    if (w >= 8) tile_write(tiles + (w - 8) * 2048, acc, lane);
    __syncthreads();
    if (w < 8)  tile_add(tiles + w * 2048, acc, lane);
    __syncthreads();
    if (w >= 4 && w < 8) tile_write(tiles + (w - 4) * 2048, acc, lane);
    __syncthreads();
    if (w < 4)  tile_add(tiles + w * 2048, acc, lane);
    __syncthreads();
    if (w == 2 || w == 3) tile_write(tiles + (w - 2) * 2048, acc, lane);
    __syncthreads();
    if (w < 2)  tile_add(tiles + w * 2048, acc, lane);   // w0: eh0, w1: eh1 full
    __syncthreads();                                     // tiles now dead

    float* logits = (float*)smem;              // [64][65]
    float* sw1 = (float*)(smem + 16640);
    float* sw2 = (float*)(smem + 16896);
    int*   si1 = (int*)  (smem + 17152);
    int*   si2 = (int*)  (smem + 17408);

    if (w < 2) {                               // write full logits tile
#pragma unroll
        for (int e = 0; e < EH; ++e)
            logits[lane * 65 + eh * EH + e] = acc[e];
    }
    __syncthreads();

    if (w == 0) {
        // lane = token: top-2 scan (+bias). Strict '>' matches top_k ties.
        float m1 = -3.4e38f, m2 = -3.4e38f;
        int i1 = 0, i2 = 0;
#pragma unroll
        for (int e = 0; e < E; ++e) {
            float v = logits[lane * 65 + e] + Bv[e];
            if (v > m1)      { m2 = m1; i2 = i1; m1 = v; i1 = e; }
            else if (v > m2) { m2 = v; i2 = e; }
        }
        float p = 1.0f / (1.0f + expf(m2 - m1));   // stable: m2 <= m1
        sw1[lane] = p; sw2[lane] = 1.0f - p;
        si1[lane] = i1; si2[lane] = i2;
    }
    __syncthreads();

    // ---- coalesced float4 store of the 64x64 tile (1024 float4) ----
    float4* o4 = (float4*)(out + (size_t)tok0 * E);
    {
        int idx = tid;                  // 0..1023
        int tl  = idx >> 4;             // token 0..63
        int e0  = (idx & 15) * 4;
        int a1 = si1[tl], a2 = si2[tl];
        float v1 = sw1[tl], v2 = sw2[tl];
        float4 v;
        v.x = (e0 + 0 == a1) ? v1 : (e0 + 0 == a2) ? v2 : 0.0f;
        v.y = (e0 + 1 == a1) ? v1 : (e0 + 1 == a2) ? v2 : 0.0f;
        v.z = (e0 + 2 == a1) ? v1 : (e0 + 2 == a2) ? v2 : 0.0f;
        v.w = (e0 + 3 == a1) ? v1 : (e0 + 3 == a2) ? v2 : 0.0f;
        o4[idx] = v;
    }
}

extern "C" void kernel_launch(void* const* d_in, const int* in_sizes, int n_in,
                              void* d_out, int out_size, void* d_ws, size_t ws_size,
                              hipStream_t stream) {
    const float* x = (const float*)d_in[0];
    const float* W = (const float*)d_in[1];
    const float* b = (const float*)d_in[2];
    float* out = (float*)d_out;

    const int tokens = in_sizes[0] / D;      // 16384
    const int blocks = tokens / TOK;         // 256

    gating_kernel<<<blocks, THREADS, 0, stream>>>(x, W, b, out);
}